// Round 7
// baseline (840.342 us; speedup 1.0000x reference)
//
#include <hip/hip_runtime.h>
#include <hip/hip_bf16.h>

#define BT 65536
#define DD 512
#define HH 512
#define NE 32
#define CAP 5120
#define BM 64
#define NRB 80   /* CAP/BM */

typedef float  f32x4  __attribute__((ext_vector_type(4)));
typedef short  bf16x8 __attribute__((ext_vector_type(8)));

__device__ __forceinline__ unsigned short f2bf(float f){
    unsigned int u = __builtin_bit_cast(unsigned int, f);
    unsigned int r = (u + 0x7fffu + ((u >> 16) & 1u)) >> 16;
    return (unsigned short)r;
}

// ---------------- weight convert to MFMA-fragment-tiled bf16 ----------------
// W[e][k][n] fp32 -> Wf[e][nt(32)][kc(16)][lane(64)][8] bf16: for fragment (nt,kc)
// lane holds W[k = kc*32 + (lane>>4)*8 + j][n = nt*16 + (lane&15)].
__global__ __launch_bounds__(256) void k_wconv(
    const float* __restrict__ W1, const float* __restrict__ W2,
    unsigned short* __restrict__ W1f, unsigned short* __restrict__ W2f)
{
    int b = blockIdx.x;                    // 512 blocks
    int w = b >> 8;                        // 0: W1, 1: W2
    int e = (b >> 3) & 31;
    int kq = b & 7;                        // k-range [kq*64, kq*64+64)
    const float* src = (w ? W2 : W1) + ((size_t)e << 18);
    unsigned short* dst = (w ? W2f : W1f) + ((size_t)e << 18);
    int t = threadIdx.x;
    #pragma unroll 1
    for (int kg = 0; kg < 8; kg++){
        int k0 = kq*64 + kg*8;
        #pragma unroll
        for (int ng = 0; ng < 2; ng++){
            int n = ng*256 + t;
            unsigned short v[8];
            #pragma unroll
            for (int j = 0; j < 8; j++)
                v[j] = f2bf(src[(size_t)(k0 + j)*512 + n]);
            int nt = n >> 4, kc = k0 >> 5, ln = ((k0 >> 3) & 3)*16 + (n & 15);
            *(bf16x8*)(dst + (((size_t)(nt*16 + kc)*64 + ln) << 3)) = *(bf16x8*)v;
        }
    }
}

// ---------------- gating v5: 4 threads per token (split-D), shuffle reduce ----------------
__global__ __launch_bounds__(256) void k_gate(
    const float* __restrict__ x, const float* __restrict__ Wg,
    float* __restrict__ y, int* __restrict__ counts,
    int* __restrict__ toks, float* __restrict__ wts)
{
    __shared__ int lcnt[NE], lbase[NE];

    int tid = threadIdx.x;
    int tl  = tid >> 2;                  // local token 0..63
    int q   = tid & 3;                   // dim-quarter
    int tok = blockIdx.x * 64 + tl;

    const float* xr = x + (size_t)tok * DD;       // full row (used by fallback)
    const float* xq = xr + q * 128;               // this thread's 128-dim slice

    float acc[NE];
    #pragma unroll
    for (int n = 0; n < NE; n++) acc[n] = 0.f;

    #pragma unroll 1
    for (int d = 0; d < 128; d += 8){
        float4 xa = *(const float4*)(xq + d);
        float4 xb = *(const float4*)(xq + d + 4);
        #pragma unroll
        for (int j = 0; j < 8; j++){
            float xv = (j < 4) ? ((j==0)?xa.x:(j==1)?xa.y:(j==2)?xa.z:xa.w)
                               : ((j==4)?xb.x:(j==5)?xb.y:(j==6)?xb.z:xb.w);
            const float4* wr = (const float4*)(Wg + (size_t)(q*128 + d + j)*NE);
            #pragma unroll
            for (int p = 0; p < 8; p++){
                float4 w4 = wr[p];
                acc[p*4+0] = fmaf(xv, w4.x, acc[p*4+0]);
                acc[p*4+1] = fmaf(xv, w4.y, acc[p*4+1]);
                acc[p*4+2] = fmaf(xv, w4.z, acc[p*4+2]);
                acc[p*4+3] = fmaf(xv, w4.w, acc[p*4+3]);
            }
        }
    }

    // combine the 4 dim-slices (lanes q=0..3 of each token group)
    #pragma unroll
    for (int n = 0; n < NE; n++){
        acc[n] += __shfl_xor(acc[n], 1, 64);
        acc[n] += __shfl_xor(acc[n], 2, 64);
    }

    int i1 = 0, i2 = 0; bool k1 = false, k2 = false;
    int g1 = 0, g2 = 0; float w1 = 0.f, w2 = 0.f;

    if (tid < NE) lcnt[tid] = 0;
    __syncthreads();

    if (q == 0){
        // top-3 in fp32 (strict > keeps lowest index on ties, matching lax.top_k)
        float v1 = -1e30f; i1 = -1;
        #pragma unroll
        for (int n = 0; n < NE; n++) if (acc[n] > v1){ v1 = acc[n]; i1 = n; }
        float v2 = -1e30f; i2 = -1;
        #pragma unroll
        for (int n = 0; n < NE; n++) if (n != i1 && acc[n] > v2){ v2 = acc[n]; i2 = n; }
        float v3 = -1e30f;
        #pragma unroll
        for (int n = 0; n < NE; n++) if (n != i1 && n != i2 && acc[n] > v3) v3 = acc[n];

        if (v2 - v3 >= 1e-4f){
            double ex  = exp((double)v2 - (double)v1);
            double inv = 1.0 / (1.0 + ex);
            w1 = (float)inv; w2 = (float)(ex * inv);
        } else {
            // rare (~1e-3): resolve the {top2} set among near-tie candidates in fp64.
            float thresh = v2 - 1e-3f;
            unsigned cmask = 0u;
            #pragma unroll
            for (int n = 0; n < NE; n++) cmask |= (acc[n] >= thresh) ? (1u << n) : 0u;

            double dv1 = -1.0e300, dv2 = -1.0e300; int di1 = -1, di2 = -1;
            #pragma unroll 1
            for (int n = 0; n < NE; n++){
                if (!((cmask >> n) & 1u)) continue;
                double s0 = 0.0, s1 = 0.0, s2 = 0.0, s3 = 0.0;
                #pragma unroll 4
                for (int d = 0; d < DD; d += 4){
                    s0 = fma((double)xr[d+0], (double)Wg[(size_t)(d+0)*NE + n], s0);
                    s1 = fma((double)xr[d+1], (double)Wg[(size_t)(d+1)*NE + n], s1);
                    s2 = fma((double)xr[d+2], (double)Wg[(size_t)(d+2)*NE + n], s2);
                    s3 = fma((double)xr[d+3], (double)Wg[(size_t)(d+3)*NE + n], s3);
                }
                double s = (s0 + s1) + (s2 + s3);
                if (s > dv1){ dv2 = dv1; di2 = di1; dv1 = s; di1 = n; }
                else if (s > dv2){ dv2 = s; di2 = n; }
            }
            i1 = di1; i2 = di2;
            double ex  = exp(dv2 - dv1);
            double inv = 1.0 / (1.0 + ex);
            w1 = (float)inv; w2 = (float)(ex * inv);
        }
        int s1 = atomicAdd(&lcnt[i1], 1);
        int s2 = atomicAdd(&lcnt[i2], 1);
        g1 = s1; g2 = s2;
    }
    __syncthreads();
    if (tid < NE && lcnt[tid] > 0) lbase[tid] = atomicAdd(&counts[tid], lcnt[tid]);
    __syncthreads();
    if (q == 0){
        g1 += lbase[i1];
        g2 += lbase[i2];
        k1 = g1 < CAP; k2 = g2 < CAP;
        if (k1){ toks[i1*CAP + g1] = tok; wts[i1*CAP + g1] = w1; }
        if (k2){ toks[i2*CAP + g2] = tok; wts[i2*CAP + g2] = w2; }
    }

    // cooperative coalesced y zero for this block's 64 rows (64*512*4B = 128KB)
    float4 z4; z4.x = 0.f; z4.y = 0.f; z4.z = 0.f; z4.w = 0.f;
    float4* yb = (float4*)(y + (size_t)blockIdx.x * 64 * DD);
    #pragma unroll 1
    for (int i = 0; i < 32; i++) yb[i*256 + tid] = z4;
    if (q == 0 && !(k1 | k2)){   // passthrough (statistically never happens)
        const float4* xr4 = (const float4*)xr;
        float4* yr4 = (float4*)(y + (size_t)tok * DD);
        #pragma unroll 1
        for (int j = 0; j < 128; j++) yr4[j] = xr4[j];
    }
}

// ---------------- fused expert FFN v4: expert-locality XCD swizzle + v3 structure ----------------
__global__ __launch_bounds__(512, 4) void k_ffn(
    const float* __restrict__ x,
    const unsigned short* __restrict__ W1f,
    const unsigned short* __restrict__ W2f,
    const float* __restrict__ b1, const float* __restrict__ b2,
    const int* __restrict__ counts,
    const int* __restrict__ toks, const float* __restrict__ wts,
    float* __restrict__ y)
{
    __shared__ unsigned char AH[64 * 1024];   // [tok(64)][512 bf16], 16B-chunk XOR swizzle ((tok&7)<<4)

    // Inverse of p = (e&7) + 8*((e>>3)*NRB + rb): all 80 blocks of expert e land on XCD e&7
    // -> per-XCD W working set ~1 MB (L2-resident).
    int p  = blockIdx.x;
    int s  = p >> 3;
    int e  = ((s / NRB) << 3) | (p & 7);
    int rb = s % NRB;

    int cnt = counts[e]; if (cnt > CAP) cnt = CAP;
    int r0 = rb * BM;
    if (r0 >= cnt) return;

    int tid  = threadIdx.x;
    int lane = tid & 63;
    int wv   = tid >> 6;      // 8 waves: wave owns hidden/output cols [wv*64, wv*64+64)
    int lg   = lane >> 4;     // quarter-wave
    int ll   = lane & 15;

    // ---- stage X: gather rows, convert to bf16, swizzled ----
    {
        int row = tid >> 3, seg = tid & 7;
        int gr  = r0 + row;
        char* rowb = (char*)AH + row * 1024;
        int rsw = (row & 7) << 4;
        if (gr < cnt){
            int tk = toks[e*CAP + gr];
            const float4* src = (const float4*)(x + (size_t)tk*DD + seg*64);
            #pragma unroll
            for (int j = 0; j < 8; j++){
                float4 f0 = src[2*j], f1 = src[2*j+1];
                bf16x8 pk;
                pk[0]=(short)f2bf(f0.x); pk[1]=(short)f2bf(f0.y); pk[2]=(short)f2bf(f0.z); pk[3]=(short)f2bf(f0.w);
                pk[4]=(short)f2bf(f1.x); pk[5]=(short)f2bf(f1.y); pk[6]=(short)f2bf(f1.z); pk[7]=(short)f2bf(f1.w);
                int chunk = seg*8 + j;
                *(bf16x8*)(rowb + ((chunk << 4) ^ rsw)) = pk;
            }
        } else {
            bf16x8 zz = (bf16x8)0;
            #pragma unroll
            for (int j = 0; j < 8; j++){
                int chunk = seg*8 + j;
                *(bf16x8*)(rowb + ((chunk << 4) ^ rsw)) = zz;
            }
        }
    }
    __syncthreads();

    f32x4 acc[4][4];          // layer1: [local ntile][toktile] ; layer2: [local dtile][toktile]
    #pragma unroll
    for (int a2 = 0; a2 < 4; a2++)
        #pragma unroll
        for (int tt = 0; tt < 4; tt++)
            acc[a2][tt] = (f32x4)0.f;

    // ---- layer 1 (swapped): acc[a][tt] += W1^T-frag(a,c) x X-frag(tt,c) ----
    {
        const unsigned short* Wa = W1f + ((size_t)e << 18) + (size_t)wv*32768;
        bf16x8 f0[4], f1[4];
        #pragma unroll
        for (int a2 = 0; a2 < 4; a2++)
            f0[a2] = *(const bf16x8*)(Wa + a2*8192 + lane*8);
        #pragma unroll 1
        for (int c = 0; c < 16; c += 2){
            #pragma unroll
            for (int a2 = 0; a2 < 4; a2++)
                f1[a2] = *(const bf16x8*)(Wa + a2*8192 + (c+1)*512 + lane*8);
            {
                bf16x8 bx[4];
                #pragma unroll
                for (int tt = 0; tt < 4; tt++){
                    int tok = tt*16 + ll;
                    int bofs = (64*c + 16*lg) ^ ((tok & 7) << 4);
                    bx[tt] = *(const bf16x8*)((char*)AH + tok*1024 + bofs);
                }
                #pragma unroll
                for (int a2 = 0; a2 < 4; a2++)
                    #pragma unroll
                    for (int tt = 0; tt < 4; tt++)
                        acc[a2][tt] = __builtin_amdgcn_mfma_f32_16x16x32_bf16(f0[a2], bx[tt], acc[a2][tt], 0, 0, 0);
            }
            if (c + 2 < 16){
                #pragma unroll
                for (int a2 = 0; a2 < 4; a2++)
                    f0[a2] = *(const bf16x8*)(Wa + a2*8192 + (c+2)*512 + lane*8);
            }
            {
                bf16x8 bx[4];
                #pragma unroll
                for (int tt = 0; tt < 4; tt++){
                    int tok = tt*16 + ll;
                    int bofs = (64*(c+1) + 16*lg) ^ ((tok & 7) << 4);
                    bx[tt] = *(const bf16x8*)((char*)AH + tok*1024 + bofs);
                }
                #pragma unroll
                for (int a2 = 0; a2 < 4; a2++)
                    #pragma unroll
                    for (int tt = 0; tt < 4; tt++)
                        acc[a2][tt] = __builtin_amdgcn_mfma_f32_16x16x32_bf16(f1[a2], bx[tt], acc[a2][tt], 0, 0, 0);
            }
        }
    }
    __syncthreads();   // all waves done reading X

    // ---- h = relu(acc + b1) -> AH as h[tok][n], packed 8B writes ----
    #pragma unroll
    for (int a2 = 0; a2 < 4; a2++){
        int n0 = wv*64 + a2*16 + lg*4;
        float4 bv = *(const float4*)(b1 + e*HH + n0);
        #pragma unroll
        for (int tt = 0; tt < 4; tt++){
            int tok = tt*16 + ll;
            float h0 = acc[a2][tt][0] + bv.x; h0 = h0 > 0.f ? h0 : 0.f;
            float h1 = acc[a2][tt][1] + bv.y; h1 = h1 > 0.f ? h1 : 0.f;
            float h2 = acc[a2][tt][2] + bv.z; h2 = h2 > 0.f ? h2 : 0.f;
            float h3 = acc[a2][tt][3] + bv.w; h3 = h3 > 0.f ? h3 : 0.f;
            uint2 pk;
            pk.x = (unsigned)f2bf(h0) | ((unsigned)f2bf(h1) << 16);
            pk.y = (unsigned)f2bf(h2) | ((unsigned)f2bf(h3) << 16);
            int bofs = (n0*2) ^ ((tok & 7) << 4);
            *(uint2*)((char*)AH + tok*1024 + bofs) = pk;
            acc[a2][tt] = (f32x4)0.f;
        }
    }
    __syncthreads();

    // ---- layer 2: acc[b][tt] += h-frag(tt,kc) @ W2-frag(b,kc) ----
    {
        const unsigned short* Wb = W2f + ((size_t)e << 18) + (size_t)wv*32768;
        bf16x8 f0[4], f1[4];
        #pragma unroll
        for (int b_ = 0; b_ < 4; b_++)
            f0[b_] = *(const bf16x8*)(Wb + b_*8192 + lane*8);
        #pragma unroll 1
        for (int kc = 0; kc < 16; kc += 2){
            #pragma unroll
            for (int b_ = 0; b_ < 4; b_++)
                f1[b_] = *(const bf16x8*)(Wb + b_*8192 + (kc+1)*512 + lane*8);
            {
                bf16x8 ah[4];
                #pragma unroll
                for (int tt = 0; tt < 4; tt++){
                    int tok = tt*16 + ll;
                    int bofs = (64*kc + 16*lg) ^ ((tok & 7) << 4);
                    ah[tt] = *(const bf16x8*)((char*)AH + tok*1024 + bofs);
                }
                #pragma unroll
                for (int b_ = 0; b_ < 4; b_++)
                    #pragma unroll
                    for (int tt = 0; tt < 4; tt++)
                        acc[b_][tt] = __builtin_amdgcn_mfma_f32_16x16x32_bf16(ah[tt], f0[b_], acc[b_][tt], 0, 0, 0);
            }
            if (kc + 2 < 16){
                #pragma unroll
                for (int b_ = 0; b_ < 4; b_++)
                    f0[b_] = *(const bf16x8*)(Wb + b_*8192 + (kc+2)*512 + lane*8);
            }
            {
                bf16x8 ah[4];
                #pragma unroll
                for (int tt = 0; tt < 4; tt++){
                    int tok = tt*16 + ll;
                    int bofs = (64*(kc+1) + 16*lg) ^ ((tok & 7) << 4);
                    ah[tt] = *(const bf16x8*)((char*)AH + tok*1024 + bofs);
                }
                #pragma unroll
                for (int b_ = 0; b_ < 4; b_++)
                    #pragma unroll
                    for (int tt = 0; tt < 4; tt++)
                        acc[b_][tt] = __builtin_amdgcn_mfma_f32_16x16x32_bf16(ah[tt], f1[b_], acc[b_][tt], 0, 0, 0);
            }
        }
    }

    // ---- epilogue: y[tok] += w * (acc + b2) ----
    float bb[4];
    #pragma unroll
    for (int b_ = 0; b_ < 4; b_++)
        bb[b_] = b2[e*DD + wv*64 + b_*16 + ll];

    #pragma unroll
    for (int tt = 0; tt < 4; tt++){
        #pragma unroll
        for (int i = 0; i < 4; i++){
            int rl = tt*16 + lg*4 + i;
            int gr = r0 + rl;
            if (gr < cnt){
                int   tk = toks[e*CAP + gr];
                float w  = wts[e*CAP + gr];
                float* yr = y + (size_t)tk * DD;
                #pragma unroll
                for (int b_ = 0; b_ < 4; b_++){
                    int col = wv*64 + b_*16 + ll;
                    atomicAdd(yr + col, w * (acc[b_][tt][i] + bb[b_]));
                }
            }
        }
    }
}

extern "C" void kernel_launch(void* const* d_in, const int* in_sizes, int n_in,
                              void* d_out, int out_size, void* d_ws, size_t ws_size,
                              hipStream_t stream)
{
    const float* x  = (const float*)d_in[0];
    const float* Wg = (const float*)d_in[1];
    const float* W1 = (const float*)d_in[2];
    const float* b1 = (const float*)d_in[3];
    const float* W2 = (const float*)d_in[4];
    const float* b2 = (const float*)d_in[5];
    float* y = (float*)d_out;

    char* ws = (char*)d_ws;
    unsigned short* W1f = (unsigned short*)(ws);
    unsigned short* W2f = (unsigned short*)(ws + 16777216);
    int*   counts = (int*)  (ws + 33554432);
    int*   toks   = (int*)  (ws + 33554432 + 256);
    float* wts    = (float*)(ws + 33554432 + 256 + 655360);

    hipMemsetAsync(counts, 0, 256, stream);
    hipLaunchKernelGGL(k_wconv, dim3(512), dim3(256), 0, stream, W1, W2, W1f, W2f);
    hipLaunchKernelGGL(k_gate,  dim3(BT/64), dim3(256), 0, stream, x, Wg, y, counts, toks, wts);
    hipLaunchKernelGGL(k_ffn,   dim3(NE*NRB), dim3(512), 0, stream, x, W1f, W2f, b1, b2, counts, toks, wts, y);
}

// Round 8
// 521.833 us; speedup vs baseline: 1.6104x; 1.6104x over previous
//
#include <hip/hip_runtime.h>
#include <hip/hip_bf16.h>

#define BT 65536
#define DD 512
#define HH 512
#define NE 32
#define CAP 5120
#define BM 64
#define NRB 80   /* CAP/BM */

typedef float  f32x4  __attribute__((ext_vector_type(4)));
typedef short  bf16x8 __attribute__((ext_vector_type(8)));

__device__ __forceinline__ unsigned short f2bf(float f){
    unsigned int u = __builtin_bit_cast(unsigned int, f);
    unsigned int r = (u + 0x7fffu + ((u >> 16) & 1u)) >> 16;
    return (unsigned short)r;
}

// ---------------- weight convert to MFMA-fragment-tiled bf16 ----------------
// W[e][k][n] fp32 -> Wf[e][nt(32)][kc(16)][lane(64)][8] bf16: for fragment (nt,kc)
// lane holds W[k = kc*32 + (lane>>4)*8 + j][n = nt*16 + (lane&15)].
__global__ __launch_bounds__(256) void k_wconv(
    const float* __restrict__ W1, const float* __restrict__ W2,
    unsigned short* __restrict__ W1f, unsigned short* __restrict__ W2f)
{
    int b = blockIdx.x;                    // 512 blocks
    int w = b >> 8;                        // 0: W1, 1: W2
    int e = (b >> 3) & 31;
    int kq = b & 7;                        // k-range [kq*64, kq*64+64)
    const float* src = (w ? W2 : W1) + ((size_t)e << 18);
    unsigned short* dst = (w ? W2f : W1f) + ((size_t)e << 18);
    int t = threadIdx.x;
    #pragma unroll 1
    for (int kg = 0; kg < 8; kg++){
        int k0 = kq*64 + kg*8;
        #pragma unroll
        for (int ng = 0; ng < 2; ng++){
            int n = ng*256 + t;
            unsigned short v[8];
            #pragma unroll
            for (int j = 0; j < 8; j++)
                v[j] = f2bf(src[(size_t)(k0 + j)*512 + n]);
            int nt = n >> 4, kc = k0 >> 5, ln = ((k0 >> 3) & 3)*16 + (n & 15);
            *(bf16x8*)(dst + (((size_t)(nt*16 + kc)*64 + ln) << 3)) = *(bf16x8*)v;
        }
    }
}

// ---------------- gating v6: 1 token/thread, wave-uniform Wg s_loads, x prefetch ----------------
__global__ __launch_bounds__(256) void k_gate(
    const float* __restrict__ x, const float* __restrict__ Wg,
    float* __restrict__ y, int* __restrict__ counts,
    int* __restrict__ toks, float* __restrict__ wts)
{
    __shared__ int lcnt[NE], lbase[NE];

    int tid = threadIdx.x;
    int tok = blockIdx.x * 256 + tid;

    const float* xr = x + (size_t)tok * DD;

    float acc[NE];
    #pragma unroll
    for (int n = 0; n < NE; n++) acc[n] = 0.f;

    // distance-1 double-buffer prefetch of x (32B/iter) hides HBM latency under 256 FMAs
    float4 xa = *(const float4*)(xr);
    float4 xb = *(const float4*)(xr + 4);
    #pragma unroll 1
    for (int d = 0; d < DD; d += 8){
        int dn = (d + 8 < DD) ? (d + 8) : 0;     // always-valid prefetch address
        float4 na = *(const float4*)(xr + dn);
        float4 nb = *(const float4*)(xr + dn + 4);
        #pragma unroll
        for (int j = 0; j < 8; j++){
            float xv = (j < 4) ? ((j==0)?xa.x:(j==1)?xa.y:(j==2)?xa.z:xa.w)
                               : ((j==4)?xb.x:(j==5)?xb.y:(j==6)?xb.z:xb.w);
            const float4* wr = (const float4*)(Wg + (size_t)(d + j)*NE);   // wave-uniform -> s_load
            #pragma unroll
            for (int q = 0; q < 8; q++){
                float4 w4 = wr[q];
                acc[q*4+0] = fmaf(xv, w4.x, acc[q*4+0]);
                acc[q*4+1] = fmaf(xv, w4.y, acc[q*4+1]);
                acc[q*4+2] = fmaf(xv, w4.z, acc[q*4+2]);
                acc[q*4+3] = fmaf(xv, w4.w, acc[q*4+3]);
            }
        }
        xa = na; xb = nb;
    }

    // top-3 in fp32 (strict > keeps lowest index on ties, matching lax.top_k)
    float v1 = -1e30f; int i1 = -1;
    #pragma unroll
    for (int n = 0; n < NE; n++) if (acc[n] > v1){ v1 = acc[n]; i1 = n; }
    float v2 = -1e30f; int i2 = -1;
    #pragma unroll
    for (int n = 0; n < NE; n++) if (n != i1 && acc[n] > v2){ v2 = acc[n]; i2 = n; }
    float v3 = -1e30f;
    #pragma unroll
    for (int n = 0; n < NE; n++) if (n != i1 && n != i2 && acc[n] > v3) v3 = acc[n];

    float w1, w2;
    if (v2 - v3 >= 1e-4f){
        double ex  = exp((double)v2 - (double)v1);
        double inv = 1.0 / (1.0 + ex);
        w1 = (float)inv; w2 = (float)(ex * inv);
    } else {
        // rare (~1e-3): resolve the {top2} set among near-tie candidates in fp64.
        float thresh = v2 - 1e-3f;
        unsigned cmask = 0u;
        #pragma unroll
        for (int n = 0; n < NE; n++) cmask |= (acc[n] >= thresh) ? (1u << n) : 0u;

        double dv1 = -1.0e300, dv2 = -1.0e300; int di1 = -1, di2 = -1;
        #pragma unroll 1
        for (int n = 0; n < NE; n++){
            if (!((cmask >> n) & 1u)) continue;
            double s0 = 0.0, s1 = 0.0, s2 = 0.0, s3 = 0.0;
            #pragma unroll 4
            for (int d = 0; d < DD; d += 4){
                s0 = fma((double)xr[d+0], (double)Wg[(size_t)(d+0)*NE + n], s0);
                s1 = fma((double)xr[d+1], (double)Wg[(size_t)(d+1)*NE + n], s1);
                s2 = fma((double)xr[d+2], (double)Wg[(size_t)(d+2)*NE + n], s2);
                s3 = fma((double)xr[d+3], (double)Wg[(size_t)(d+3)*NE + n], s3);
            }
            double s = (s0 + s1) + (s2 + s3);
            if (s > dv1){ dv2 = dv1; di2 = di1; dv1 = s; di1 = n; }
            else if (s > dv2){ dv2 = s; di2 = n; }
        }
        i1 = di1; i2 = di2;
        double ex  = exp(dv2 - dv1);
        double inv = 1.0 / (1.0 + ex);
        w1 = (float)inv; w2 = (float)(ex * inv);
    }

    // two-level slot assignment
    if (tid < NE) lcnt[tid] = 0;
    __syncthreads();
    int s1 = atomicAdd(&lcnt[i1], 1);
    int s2 = atomicAdd(&lcnt[i2], 1);
    __syncthreads();
    if (tid < NE && lcnt[tid] > 0) lbase[tid] = atomicAdd(&counts[tid], lcnt[tid]);
    __syncthreads();
    int g1 = lbase[i1] + s1;
    int g2 = lbase[i2] + s2;
    bool k1 = g1 < CAP, k2 = g2 < CAP;
    if (k1){ toks[i1*CAP + g1] = tok; wts[i1*CAP + g1] = w1; }
    if (k2){ toks[i2*CAP + g2] = tok; wts[i2*CAP + g2] = w2; }

    // y is zeroed by hipMemsetAsync before this kernel; only passthrough writes here
    if (!(k1 | k2)){   // statistically never happens
        const float4* xr4 = (const float4*)xr;
        float4* yr4 = (float4*)(y + (size_t)tok * DD);
        #pragma unroll 1
        for (int j = 0; j < 128; j++) yr4[j] = xr4[j];
    }
}

// ---------------- fused expert FFN v4: expert-locality XCD swizzle + swapped layer-1 ----------------
__global__ __launch_bounds__(512, 4) void k_ffn(
    const float* __restrict__ x,
    const unsigned short* __restrict__ W1f,
    const unsigned short* __restrict__ W2f,
    const float* __restrict__ b1, const float* __restrict__ b2,
    const int* __restrict__ counts,
    const int* __restrict__ toks, const float* __restrict__ wts,
    float* __restrict__ y)
{
    __shared__ unsigned char AH[64 * 1024];   // [tok(64)][512 bf16], 16B-chunk XOR swizzle ((tok&7)<<4)

    // Inverse of p = (e&7) + 8*((e>>3)*NRB + rb): all 80 blocks of expert e land on XCD e&7
    int p  = blockIdx.x;
    int s  = p >> 3;
    int e  = ((s / NRB) << 3) | (p & 7);
    int rb = s % NRB;

    int cnt = counts[e]; if (cnt > CAP) cnt = CAP;
    int r0 = rb * BM;
    if (r0 >= cnt) return;

    int tid  = threadIdx.x;
    int lane = tid & 63;
    int wv   = tid >> 6;      // 8 waves: wave owns hidden/output cols [wv*64, wv*64+64)
    int lg   = lane >> 4;     // quarter-wave
    int ll   = lane & 15;

    // ---- stage X: gather rows, convert to bf16, swizzled ----
    {
        int row = tid >> 3, seg = tid & 7;
        int gr  = r0 + row;
        char* rowb = (char*)AH + row * 1024;
        int rsw = (row & 7) << 4;
        if (gr < cnt){
            int tk = toks[e*CAP + gr];
            const float4* src = (const float4*)(x + (size_t)tk*DD + seg*64);
            #pragma unroll
            for (int j = 0; j < 8; j++){
                float4 f0 = src[2*j], f1 = src[2*j+1];
                bf16x8 pk;
                pk[0]=(short)f2bf(f0.x); pk[1]=(short)f2bf(f0.y); pk[2]=(short)f2bf(f0.z); pk[3]=(short)f2bf(f0.w);
                pk[4]=(short)f2bf(f1.x); pk[5]=(short)f2bf(f1.y); pk[6]=(short)f2bf(f1.z); pk[7]=(short)f2bf(f1.w);
                int chunk = seg*8 + j;
                *(bf16x8*)(rowb + ((chunk << 4) ^ rsw)) = pk;
            }
        } else {
            bf16x8 zz = (bf16x8)0;
            #pragma unroll
            for (int j = 0; j < 8; j++){
                int chunk = seg*8 + j;
                *(bf16x8*)(rowb + ((chunk << 4) ^ rsw)) = zz;
            }
        }
    }
    __syncthreads();

    f32x4 acc[4][4];          // layer1: [local ntile][toktile] ; layer2: [local dtile][toktile]
    #pragma unroll
    for (int a2 = 0; a2 < 4; a2++)
        #pragma unroll
        for (int tt = 0; tt < 4; tt++)
            acc[a2][tt] = (f32x4)0.f;

    // ---- layer 1 (swapped): acc[a][tt] += W1^T-frag(a,c) x X-frag(tt,c) ----
    {
        const unsigned short* Wa = W1f + ((size_t)e << 18) + (size_t)wv*32768;
        bf16x8 f0[4], f1[4];
        #pragma unroll
        for (int a2 = 0; a2 < 4; a2++)
            f0[a2] = *(const bf16x8*)(Wa + a2*8192 + lane*8);
        #pragma unroll 1
        for (int c = 0; c < 16; c += 2){
            #pragma unroll
            for (int a2 = 0; a2 < 4; a2++)
                f1[a2] = *(const bf16x8*)(Wa + a2*8192 + (c+1)*512 + lane*8);
            {
                bf16x8 bx[4];
                #pragma unroll
                for (int tt = 0; tt < 4; tt++){
                    int tok = tt*16 + ll;
                    int bofs = (64*c + 16*lg) ^ ((tok & 7) << 4);
                    bx[tt] = *(const bf16x8*)((char*)AH + tok*1024 + bofs);
                }
                #pragma unroll
                for (int a2 = 0; a2 < 4; a2++)
                    #pragma unroll
                    for (int tt = 0; tt < 4; tt++)
                        acc[a2][tt] = __builtin_amdgcn_mfma_f32_16x16x32_bf16(f0[a2], bx[tt], acc[a2][tt], 0, 0, 0);
            }
            if (c + 2 < 16){
                #pragma unroll
                for (int a2 = 0; a2 < 4; a2++)
                    f0[a2] = *(const bf16x8*)(Wa + a2*8192 + (c+2)*512 + lane*8);
            }
            {
                bf16x8 bx[4];
                #pragma unroll
                for (int tt = 0; tt < 4; tt++){
                    int tok = tt*16 + ll;
                    int bofs = (64*(c+1) + 16*lg) ^ ((tok & 7) << 4);
                    bx[tt] = *(const bf16x8*)((char*)AH + tok*1024 + bofs);
                }
                #pragma unroll
                for (int a2 = 0; a2 < 4; a2++)
                    #pragma unroll
                    for (int tt = 0; tt < 4; tt++)
                        acc[a2][tt] = __builtin_amdgcn_mfma_f32_16x16x32_bf16(f1[a2], bx[tt], acc[a2][tt], 0, 0, 0);
            }
        }
    }
    __syncthreads();   // all waves done reading X

    // ---- h = relu(acc + b1) -> AH as h[tok][n], packed 8B writes ----
    #pragma unroll
    for (int a2 = 0; a2 < 4; a2++){
        int n0 = wv*64 + a2*16 + lg*4;
        float4 bv = *(const float4*)(b1 + e*HH + n0);
        #pragma unroll
        for (int tt = 0; tt < 4; tt++){
            int tok = tt*16 + ll;
            float h0 = acc[a2][tt][0] + bv.x; h0 = h0 > 0.f ? h0 : 0.f;
            float h1 = acc[a2][tt][1] + bv.y; h1 = h1 > 0.f ? h1 : 0.f;
            float h2 = acc[a2][tt][2] + bv.z; h2 = h2 > 0.f ? h2 : 0.f;
            float h3 = acc[a2][tt][3] + bv.w; h3 = h3 > 0.f ? h3 : 0.f;
            uint2 pk;
            pk.x = (unsigned)f2bf(h0) | ((unsigned)f2bf(h1) << 16);
            pk.y = (unsigned)f2bf(h2) | ((unsigned)f2bf(h3) << 16);
            int bofs = (n0*2) ^ ((tok & 7) << 4);
            *(uint2*)((char*)AH + tok*1024 + bofs) = pk;
            acc[a2][tt] = (f32x4)0.f;
        }
    }
    __syncthreads();

    // ---- layer 2: acc[b][tt] += h-frag(tt,kc) @ W2-frag(b,kc) ----
    {
        const unsigned short* Wb = W2f + ((size_t)e << 18) + (size_t)wv*32768;
        bf16x8 f0[4], f1[4];
        #pragma unroll
        for (int b_ = 0; b_ < 4; b_++)
            f0[b_] = *(const bf16x8*)(Wb + b_*8192 + lane*8);
        #pragma unroll 1
        for (int kc = 0; kc < 16; kc += 2){
            #pragma unroll
            for (int b_ = 0; b_ < 4; b_++)
                f1[b_] = *(const bf16x8*)(Wb + b_*8192 + (kc+1)*512 + lane*8);
            {
                bf16x8 ah[4];
                #pragma unroll
                for (int tt = 0; tt < 4; tt++){
                    int tok = tt*16 + ll;
                    int bofs = (64*kc + 16*lg) ^ ((tok & 7) << 4);
                    ah[tt] = *(const bf16x8*)((char*)AH + tok*1024 + bofs);
                }
                #pragma unroll
                for (int b_ = 0; b_ < 4; b_++)
                    #pragma unroll
                    for (int tt = 0; tt < 4; tt++)
                        acc[b_][tt] = __builtin_amdgcn_mfma_f32_16x16x32_bf16(ah[tt], f0[b_], acc[b_][tt], 0, 0, 0);
            }
            if (kc + 2 < 16){
                #pragma unroll
                for (int b_ = 0; b_ < 4; b_++)
                    f0[b_] = *(const bf16x8*)(Wb + b_*8192 + (kc+2)*512 + lane*8);
            }
            {
                bf16x8 ah[4];
                #pragma unroll
                for (int tt = 0; tt < 4; tt++){
                    int tok = tt*16 + ll;
                    int bofs = (64*(kc+1) + 16*lg) ^ ((tok & 7) << 4);
                    ah[tt] = *(const bf16x8*)((char*)AH + tok*1024 + bofs);
                }
                #pragma unroll
                for (int b_ = 0; b_ < 4; b_++)
                    #pragma unroll
                    for (int tt = 0; tt < 4; tt++)
                        acc[b_][tt] = __builtin_amdgcn_mfma_f32_16x16x32_bf16(ah[tt], f1[b_], acc[b_][tt], 0, 0, 0);
            }
        }
    }

    // ---- epilogue: y[tok] += w * (acc + b2) ----
    float bb[4];
    #pragma unroll
    for (int b_ = 0; b_ < 4; b_++)
        bb[b_] = b2[e*DD + wv*64 + b_*16 + ll];

    #pragma unroll
    for (int tt = 0; tt < 4; tt++){
        #pragma unroll
        for (int i = 0; i < 4; i++){
            int rl = tt*16 + lg*4 + i;
            int gr = r0 + rl;
            if (gr < cnt){
                int   tk = toks[e*CAP + gr];
                float w  = wts[e*CAP + gr];
                float* yr = y + (size_t)tk * DD;
                #pragma unroll
                for (int b_ = 0; b_ < 4; b_++){
                    int col = wv*64 + b_*16 + ll;
                    atomicAdd(yr + col, w * (acc[b_][tt][i] + bb[b_]));
                }
            }
        }
    }
}

extern "C" void kernel_launch(void* const* d_in, const int* in_sizes, int n_in,
                              void* d_out, int out_size, void* d_ws, size_t ws_size,
                              hipStream_t stream)
{
    const float* x  = (const float*)d_in[0];
    const float* Wg = (const float*)d_in[1];
    const float* W1 = (const float*)d_in[2];
    const float* b1 = (const float*)d_in[3];
    const float* W2 = (const float*)d_in[4];
    const float* b2 = (const float*)d_in[5];
    float* y = (float*)d_out;

    char* ws = (char*)d_ws;
    unsigned short* W1f = (unsigned short*)(ws);
    unsigned short* W2f = (unsigned short*)(ws + 16777216);
    int*   counts = (int*)  (ws + 33554432);
    int*   toks   = (int*)  (ws + 33554432 + 256);
    float* wts    = (float*)(ws + 33554432 + 256 + 655360);

    hipMemsetAsync(counts, 0, 256, stream);
    hipMemsetAsync(y, 0, (size_t)out_size * sizeof(float), stream);
    hipLaunchKernelGGL(k_wconv, dim3(512), dim3(256), 0, stream, W1, W2, W1f, W2f);
    hipLaunchKernelGGL(k_gate,  dim3(BT/256), dim3(256), 0, stream, x, Wg, y, counts, toks, wts);
    hipLaunchKernelGGL(k_ffn,   dim3(NE*NRB), dim3(512), 0, stream, x, W1f, W2f, b1, b2, counts, toks, wts, y);
}

// Round 9
// 417.314 us; speedup vs baseline: 2.0137x; 1.2505x over previous
//
#include <hip/hip_runtime.h>
#include <hip/hip_bf16.h>

#define BT 65536
#define DD 512
#define HH 512
#define NE 32
#define CAP 5120
#define BM 64
#define NRB 80   /* CAP/BM */

typedef float  f32x4  __attribute__((ext_vector_type(4)));
typedef short  bf16x8 __attribute__((ext_vector_type(8)));

__device__ __forceinline__ unsigned short f2bf(float f){
    unsigned int u = __builtin_bit_cast(unsigned int, f);
    unsigned int r = (u + 0x7fffu + ((u >> 16) & 1u)) >> 16;
    return (unsigned short)r;
}

// ---------------- weight convert to MFMA-fragment-tiled bf16 ----------------
// W[e][k][n] fp32 -> Wf[e][nt(32)][kc(16)][lane(64)][8] bf16: for fragment (nt,kc)
// lane holds W[k = kc*32 + (lane>>4)*8 + j][n = nt*16 + (lane&15)].
__global__ __launch_bounds__(256) void k_wconv(
    const float* __restrict__ W1, const float* __restrict__ W2,
    unsigned short* __restrict__ W1f, unsigned short* __restrict__ W2f)
{
    int b = blockIdx.x;                    // 512 blocks
    int w = b >> 8;                        // 0: W1, 1: W2
    int e = (b >> 3) & 31;
    int kq = b & 7;                        // k-range [kq*64, kq*64+64)
    const float* src = (w ? W2 : W1) + ((size_t)e << 18);
    unsigned short* dst = (w ? W2f : W1f) + ((size_t)e << 18);
    int t = threadIdx.x;
    #pragma unroll 1
    for (int kg = 0; kg < 8; kg++){
        int k0 = kq*64 + kg*8;
        #pragma unroll
        for (int ng = 0; ng < 2; ng++){
            int n = ng*256 + t;
            unsigned short v[8];
            #pragma unroll
            for (int j = 0; j < 8; j++)
                v[j] = f2bf(src[(size_t)(k0 + j)*512 + n]);
            int nt = n >> 4, kc = k0 >> 5, ln = ((k0 >> 3) & 3)*16 + (n & 15);
            *(bf16x8*)(dst + (((size_t)(nt*16 + kc)*64 + ln) << 3)) = *(bf16x8*)v;
        }
    }
}

// ---------------- gating v7: wave=dim-quarter, lane=token; 1024 blocks; LDS reduce ----------------
__global__ __launch_bounds__(256) void k_gate(
    const float* __restrict__ x, const float* __restrict__ Wg,
    int* __restrict__ counts, int* __restrict__ gsl, float* __restrict__ wts,
    unsigned char* __restrict__ flags)
{
    __shared__ float pacc[4][64][36];   // [quarter][token][expert], padded
    __shared__ int lcnt[NE], lbase[NE];

    int tid = threadIdx.x;
    int l   = tid & 63;                                    // local token
    int q   = __builtin_amdgcn_readfirstlane(tid >> 6);    // dim-quarter (wave-uniform)

    const float* xq = x + ((size_t)(blockIdx.x*64 + l))*DD + q*128;

    float acc[NE];
    #pragma unroll
    for (int n = 0; n < NE; n++) acc[n] = 0.f;

    float4 xa = *(const float4*)(xq);
    float4 xb = *(const float4*)(xq + 4);
    #pragma unroll 1
    for (int d = 0; d < 128; d += 8){
        int dn = (d + 8 < 128) ? (d + 8) : 0;
        float4 na = *(const float4*)(xq + dn);
        float4 nb = *(const float4*)(xq + dn + 4);
        #pragma unroll
        for (int j = 0; j < 8; j++){
            float xv = (j < 4) ? ((j==0)?xa.x:(j==1)?xa.y:(j==2)?xa.z:xa.w)
                               : ((j==4)?xb.x:(j==5)?xb.y:(j==6)?xb.z:xb.w);
            const float4* wr = (const float4*)(Wg + (size_t)(q*128 + d + j)*NE); // uniform -> s_load
            #pragma unroll
            for (int p = 0; p < 8; p++){
                float4 w4 = wr[p];
                acc[p*4+0] = fmaf(xv, w4.x, acc[p*4+0]);
                acc[p*4+1] = fmaf(xv, w4.y, acc[p*4+1]);
                acc[p*4+2] = fmaf(xv, w4.z, acc[p*4+2]);
                acc[p*4+3] = fmaf(xv, w4.w, acc[p*4+3]);
            }
        }
        xa = na; xb = nb;
    }

    #pragma unroll
    for (int n4 = 0; n4 < 8; n4++){
        float4 v; v.x = acc[n4*4]; v.y = acc[n4*4+1]; v.z = acc[n4*4+2]; v.w = acc[n4*4+3];
        *(float4*)&pacc[q][l][n4*4] = v;
    }
    if (tid < NE) lcnt[tid] = 0;
    __syncthreads();

    bool owner = (q == (l & 3));
    int tok = blockIdx.x*64 + l;
    int i1 = 0, i2 = 0, g1 = 0, g2 = 0;
    float w1 = 0.f, w2 = 0.f;

    if (owner){
        #pragma unroll
        for (int n4 = 0; n4 < 8; n4++){
            float4 p0 = *(float4*)&pacc[0][l][n4*4];
            float4 p1 = *(float4*)&pacc[1][l][n4*4];
            float4 p2 = *(float4*)&pacc[2][l][n4*4];
            float4 p3 = *(float4*)&pacc[3][l][n4*4];
            acc[n4*4+0] = (p0.x + p1.x) + (p2.x + p3.x);
            acc[n4*4+1] = (p0.y + p1.y) + (p2.y + p3.y);
            acc[n4*4+2] = (p0.z + p1.z) + (p2.z + p3.z);
            acc[n4*4+3] = (p0.w + p1.w) + (p2.w + p3.w);
        }

        float v1 = -1e30f; i1 = -1;
        #pragma unroll
        for (int n = 0; n < NE; n++) if (acc[n] > v1){ v1 = acc[n]; i1 = n; }
        float v2 = -1e30f; i2 = -1;
        #pragma unroll
        for (int n = 0; n < NE; n++) if (n != i1 && acc[n] > v2){ v2 = acc[n]; i2 = n; }
        float v3 = -1e30f;
        #pragma unroll
        for (int n = 0; n < NE; n++) if (n != i1 && n != i2 && acc[n] > v3) v3 = acc[n];

        if (v2 - v3 >= 1e-4f){
            double ex  = exp((double)v2 - (double)v1);
            double inv = 1.0 / (1.0 + ex);
            w1 = (float)inv; w2 = (float)(ex * inv);
        } else {
            // rare: resolve {top2} among near-tie candidates in fp64
            const float* xr = x + (size_t)tok * DD;
            float thresh = v2 - 1e-3f;
            unsigned cmask = 0u;
            #pragma unroll
            for (int n = 0; n < NE; n++) cmask |= (acc[n] >= thresh) ? (1u << n) : 0u;
            double dv1 = -1.0e300, dv2 = -1.0e300; int di1 = -1, di2 = -1;
            #pragma unroll 1
            for (int n = 0; n < NE; n++){
                if (!((cmask >> n) & 1u)) continue;
                double s0 = 0.0, s1 = 0.0, s2 = 0.0, s3 = 0.0;
                #pragma unroll 4
                for (int d = 0; d < DD; d += 4){
                    s0 = fma((double)xr[d+0], (double)Wg[(size_t)(d+0)*NE + n], s0);
                    s1 = fma((double)xr[d+1], (double)Wg[(size_t)(d+1)*NE + n], s1);
                    s2 = fma((double)xr[d+2], (double)Wg[(size_t)(d+2)*NE + n], s2);
                    s3 = fma((double)xr[d+3], (double)Wg[(size_t)(d+3)*NE + n], s3);
                }
                double s = (s0 + s1) + (s2 + s3);
                if (s > dv1){ dv2 = dv1; di2 = di1; dv1 = s; di1 = n; }
                else if (s > dv2){ dv2 = s; di2 = n; }
            }
            i1 = di1; i2 = di2;
            double ex  = exp(dv2 - dv1);
            double inv = 1.0 / (1.0 + ex);
            w1 = (float)inv; w2 = (float)(ex * inv);
        }
        g1 = atomicAdd(&lcnt[i1], 1);
        g2 = atomicAdd(&lcnt[i2], 1);
    }
    __syncthreads();
    if (tid < NE && lcnt[tid] > 0) lbase[tid] = atomicAdd(&counts[tid], lcnt[tid]);
    __syncthreads();
    if (owner){
        g1 += lbase[i1];
        g2 += lbase[i2];
        bool k1 = g1 < CAP, k2 = g2 < CAP;
        if (k1){ gsl[i1*CAP + g1] = tok;               wts[i1*CAP + g1] = w1; }
        if (k2){ gsl[i2*CAP + g2] = tok | (1 << 20);   wts[i2*CAP + g2] = w2; }
        flags[tok] = (unsigned char)((k1 ? 1 : 0) | (k2 ? 2 : 0));
    }
}

// ---------------- fused expert FFN v5: plain-store split-destination epilogue ----------------
__global__ __launch_bounds__(512, 4) void k_ffn(
    const float* __restrict__ x,
    const unsigned short* __restrict__ W1f,
    const unsigned short* __restrict__ W2f,
    const float* __restrict__ b1, const float* __restrict__ b2,
    const int* __restrict__ counts,
    const int* __restrict__ gsl, const float* __restrict__ wts,
    float* __restrict__ y, float* __restrict__ y2)
{
    __shared__ unsigned char AH[64 * 1024];   // [tok(64)][512 bf16], 16B-chunk XOR swizzle ((tok&7)<<4)

    int p  = blockIdx.x;
    int s  = p >> 3;
    int e  = ((s / NRB) << 3) | (p & 7);
    int rb = s % NRB;

    int cnt = counts[e]; if (cnt > CAP) cnt = CAP;
    int r0 = rb * BM;
    if (r0 >= cnt) return;

    int tid  = threadIdx.x;
    int lane = tid & 63;
    int wv   = tid >> 6;      // 8 waves: wave owns hidden/output cols [wv*64, wv*64+64)
    int lg   = lane >> 4;     // quarter-wave
    int ll   = lane & 15;

    // ---- stage X: gather rows, convert to bf16, swizzled ----
    {
        int row = tid >> 3, seg = tid & 7;
        int gr  = r0 + row;
        char* rowb = (char*)AH + row * 1024;
        int rsw = (row & 7) << 4;
        if (gr < cnt){
            int tk = gsl[e*CAP + gr] & 0xFFFFF;
            const float4* src = (const float4*)(x + (size_t)tk*DD + seg*64);
            #pragma unroll
            for (int j = 0; j < 8; j++){
                float4 f0 = src[2*j], f1 = src[2*j+1];
                bf16x8 pk;
                pk[0]=(short)f2bf(f0.x); pk[1]=(short)f2bf(f0.y); pk[2]=(short)f2bf(f0.z); pk[3]=(short)f2bf(f0.w);
                pk[4]=(short)f2bf(f1.x); pk[5]=(short)f2bf(f1.y); pk[6]=(short)f2bf(f1.z); pk[7]=(short)f2bf(f1.w);
                int chunk = seg*8 + j;
                *(bf16x8*)(rowb + ((chunk << 4) ^ rsw)) = pk;
            }
        } else {
            bf16x8 zz = (bf16x8)0;
            #pragma unroll
            for (int j = 0; j < 8; j++){
                int chunk = seg*8 + j;
                *(bf16x8*)(rowb + ((chunk << 4) ^ rsw)) = zz;
            }
        }
    }
    __syncthreads();

    f32x4 acc[4][4];
    #pragma unroll
    for (int a2 = 0; a2 < 4; a2++)
        #pragma unroll
        for (int tt = 0; tt < 4; tt++)
            acc[a2][tt] = (f32x4)0.f;

    // ---- layer 1 (swapped): acc[a][tt] += W1^T-frag(a,c) x X-frag(tt,c) ----
    {
        const unsigned short* Wa = W1f + ((size_t)e << 18) + (size_t)wv*32768;
        bf16x8 f0[4], f1[4];
        #pragma unroll
        for (int a2 = 0; a2 < 4; a2++)
            f0[a2] = *(const bf16x8*)(Wa + a2*8192 + lane*8);
        #pragma unroll 1
        for (int c = 0; c < 16; c += 2){
            #pragma unroll
            for (int a2 = 0; a2 < 4; a2++)
                f1[a2] = *(const bf16x8*)(Wa + a2*8192 + (c+1)*512 + lane*8);
            {
                bf16x8 bx[4];
                #pragma unroll
                for (int tt = 0; tt < 4; tt++){
                    int tok = tt*16 + ll;
                    int bofs = (64*c + 16*lg) ^ ((tok & 7) << 4);
                    bx[tt] = *(const bf16x8*)((char*)AH + tok*1024 + bofs);
                }
                #pragma unroll
                for (int a2 = 0; a2 < 4; a2++)
                    #pragma unroll
                    for (int tt = 0; tt < 4; tt++)
                        acc[a2][tt] = __builtin_amdgcn_mfma_f32_16x16x32_bf16(f0[a2], bx[tt], acc[a2][tt], 0, 0, 0);
            }
            if (c + 2 < 16){
                #pragma unroll
                for (int a2 = 0; a2 < 4; a2++)
                    f0[a2] = *(const bf16x8*)(Wa + a2*8192 + (c+2)*512 + lane*8);
            }
            {
                bf16x8 bx[4];
                #pragma unroll
                for (int tt = 0; tt < 4; tt++){
                    int tok = tt*16 + ll;
                    int bofs = (64*(c+1) + 16*lg) ^ ((tok & 7) << 4);
                    bx[tt] = *(const bf16x8*)((char*)AH + tok*1024 + bofs);
                }
                #pragma unroll
                for (int a2 = 0; a2 < 4; a2++)
                    #pragma unroll
                    for (int tt = 0; tt < 4; tt++)
                        acc[a2][tt] = __builtin_amdgcn_mfma_f32_16x16x32_bf16(f1[a2], bx[tt], acc[a2][tt], 0, 0, 0);
            }
        }
    }
    __syncthreads();

    // ---- h = relu(acc + b1) -> AH as h[tok][n], packed 8B writes ----
    #pragma unroll
    for (int a2 = 0; a2 < 4; a2++){
        int n0 = wv*64 + a2*16 + lg*4;
        float4 bv = *(const float4*)(b1 + e*HH + n0);
        #pragma unroll
        for (int tt = 0; tt < 4; tt++){
            int tok = tt*16 + ll;
            float h0 = acc[a2][tt][0] + bv.x; h0 = h0 > 0.f ? h0 : 0.f;
            float h1 = acc[a2][tt][1] + bv.y; h1 = h1 > 0.f ? h1 : 0.f;
            float h2 = acc[a2][tt][2] + bv.z; h2 = h2 > 0.f ? h2 : 0.f;
            float h3 = acc[a2][tt][3] + bv.w; h3 = h3 > 0.f ? h3 : 0.f;
            uint2 pk;
            pk.x = (unsigned)f2bf(h0) | ((unsigned)f2bf(h1) << 16);
            pk.y = (unsigned)f2bf(h2) | ((unsigned)f2bf(h3) << 16);
            int bofs = (n0*2) ^ ((tok & 7) << 4);
            *(uint2*)((char*)AH + tok*1024 + bofs) = pk;
            acc[a2][tt] = (f32x4)0.f;
        }
    }
    __syncthreads();

    // ---- layer 2: acc[b][tt] += h-frag(tt,kc) @ W2-frag(b,kc) ----
    {
        const unsigned short* Wb = W2f + ((size_t)e << 18) + (size_t)wv*32768;
        bf16x8 f0[4], f1[4];
        #pragma unroll
        for (int b_ = 0; b_ < 4; b_++)
            f0[b_] = *(const bf16x8*)(Wb + b_*8192 + lane*8);
        #pragma unroll 1
        for (int kc = 0; kc < 16; kc += 2){
            #pragma unroll
            for (int b_ = 0; b_ < 4; b_++)
                f1[b_] = *(const bf16x8*)(Wb + b_*8192 + (kc+1)*512 + lane*8);
            {
                bf16x8 ah[4];
                #pragma unroll
                for (int tt = 0; tt < 4; tt++){
                    int tok = tt*16 + ll;
                    int bofs = (64*kc + 16*lg) ^ ((tok & 7) << 4);
                    ah[tt] = *(const bf16x8*)((char*)AH + tok*1024 + bofs);
                }
                #pragma unroll
                for (int b_ = 0; b_ < 4; b_++)
                    #pragma unroll
                    for (int tt = 0; tt < 4; tt++)
                        acc[b_][tt] = __builtin_amdgcn_mfma_f32_16x16x32_bf16(ah[tt], f0[b_], acc[b_][tt], 0, 0, 0);
            }
            if (kc + 2 < 16){
                #pragma unroll
                for (int b_ = 0; b_ < 4; b_++)
                    f0[b_] = *(const bf16x8*)(Wb + b_*8192 + (kc+2)*512 + lane*8);
            }
            {
                bf16x8 ah[4];
                #pragma unroll
                for (int tt = 0; tt < 4; tt++){
                    int tok = tt*16 + ll;
                    int bofs = (64*(kc+1) + 16*lg) ^ ((tok & 7) << 4);
                    ah[tt] = *(const bf16x8*)((char*)AH + tok*1024 + bofs);
                }
                #pragma unroll
                for (int b_ = 0; b_ < 4; b_++)
                    #pragma unroll
                    for (int tt = 0; tt < 4; tt++)
                        acc[b_][tt] = __builtin_amdgcn_mfma_f32_16x16x32_bf16(ah[tt], f1[b_], acc[b_][tt], 0, 0, 0);
            }
        }
    }

    // ---- epilogue: plain stores; top-1 rows -> y, top-2 rows -> y2 ----
    float bb[4];
    #pragma unroll
    for (int b_ = 0; b_ < 4; b_++)
        bb[b_] = b2[e*DD + wv*64 + b_*16 + ll];

    #pragma unroll
    for (int tt = 0; tt < 4; tt++){
        #pragma unroll
        for (int i = 0; i < 4; i++){
            int rl = tt*16 + lg*4 + i;
            int gr = r0 + rl;
            if (gr < cnt){
                int   v  = gsl[e*CAP + gr];
                int   tk = v & 0xFFFFF;
                float w  = wts[e*CAP + gr];
                float* dst = ((v >> 20) ? y2 : y) + (size_t)tk * DD;
                #pragma unroll
                for (int b_ = 0; b_ < 4; b_++){
                    int col = wv*64 + b_*16 + ll;
                    dst[col] = w * (acc[b_][tt][i] + bb[b_]);
                }
            }
        }
    }
}

// ---------------- combine: y = [k1]y + [k2]y2, or passthrough x ----------------
__global__ __launch_bounds__(256) void k_comb(
    const float* __restrict__ x, const float* __restrict__ y2,
    const unsigned char* __restrict__ flags, float* __restrict__ y)
{
    const float4* x4  = (const float4*)x;
    const float4* y24 = (const float4*)y2;
    float4* y4 = (float4*)y;
    int nthreads = gridDim.x * 256;
    int g = blockIdx.x * 256 + threadIdx.x;
    #pragma unroll 1
    for (long long idx = g; idx < (long long)BT * 128; idx += nthreads){
        int t = (int)(idx >> 7);
        int f = flags[t];
        if (f == 3){
            float4 a = y4[idx], b = y24[idx];
            a.x += b.x; a.y += b.y; a.z += b.z; a.w += b.w;
            y4[idx] = a;
        } else if (f == 2){
            y4[idx] = y24[idx];
        } else if (f == 0){
            y4[idx] = x4[idx];
        } // f == 1: y already correct
    }
}

extern "C" void kernel_launch(void* const* d_in, const int* in_sizes, int n_in,
                              void* d_out, int out_size, void* d_ws, size_t ws_size,
                              hipStream_t stream)
{
    const float* x  = (const float*)d_in[0];
    const float* Wg = (const float*)d_in[1];
    const float* W1 = (const float*)d_in[2];
    const float* b1 = (const float*)d_in[3];
    const float* W2 = (const float*)d_in[4];
    const float* b2 = (const float*)d_in[5];
    float* y = (float*)d_out;

    char* ws = (char*)d_ws;
    unsigned short* W1f = (unsigned short*)(ws);
    unsigned short* W2f = (unsigned short*)(ws + 16777216);
    int*   counts = (int*)  (ws + 33554432);
    int*   gsl    = (int*)  (ws + 33554432 + 256);
    float* wts    = (float*)(ws + 33554432 + 256 + 655360);
    unsigned char* flags = (unsigned char*)(ws + 33554432 + 256 + 2*655360);
    float* y2     = (float*)(ws + 35651584);   // 34 MB offset, 134.2 MB

    hipMemsetAsync(counts, 0, 256, stream);
    hipLaunchKernelGGL(k_wconv, dim3(512), dim3(256), 0, stream, W1, W2, W1f, W2f);
    hipLaunchKernelGGL(k_gate,  dim3(BT/64), dim3(256), 0, stream, x, Wg, counts, gsl, wts, flags);
    hipLaunchKernelGGL(k_ffn,   dim3(NE*NRB), dim3(512), 0, stream, x, W1f, W2f, b1, b2, counts, gsl, wts, y, y2);
    hipLaunchKernelGGL(k_comb,  dim3(2048), dim3(256), 0, stream, x, y2, flags, y);
}